// Round 4
// baseline (64571.277 us; speedup 1.0000x reference)
//
#include <hip/hip_runtime.h>
#include <stdint.h>
#include <math.h>

// Persistent barrier-free 2-layer LSTM rollout, MI355X (gfx950).
// v5 = v4 with ONE structural change: candidates are published BEFORE h1
// (E-block moved between C and D). v4's loss was diagnosed as guaranteed-
// stale candidate polls: cands were stored ~0.3us AFTER h1, so consumers
// (whose cand loads issue at h1-spin exit) always read stale tags and the
// sequential lazy spin serialized ~8 LLC round-trips (~2us/step). With
// cands stored ~0.5us BEFORE h1, h1-visibility implies cand-visibility:
// zero respins in the common case.
//
//   per step (ONE broadcast round):
//     A: poll h1(t)                    [v1 lazy spin, 8 slots/lane]
//     (issue cand loads; RT hides under B)
//     B: z=W2.h1 -> p -> s(t) -> logp/out
//     C: select candidate h0(t+1)|s(t) [fresh: published before h1(t)]
//     E: 8 Whh0 rows -> candidates h0(t+2)|s'=0,1 -> publish (FIRST)
//     D: 16 rows (Wih1@h0(t+1), Whh1@h1(t)) -> h1(t+1) -> publish (LAST)
//     F: RNG u(t+1) (shadow)
//
// Interlocks (parity double-buffer, unchanged from v4):
//  - cand tag t+3 (step t's E) overwrites tag t+1: E follows C's full poll
//    of tag t+2 => all waves ran E(t-1) => all passed C(t-1) => consumed t+1.
//  - h1 tag t+2 (step t's D) overwrites tag t: D follows A's full poll of
//    tag t+1 => all waves ran D(t-1) => all passed A(t-1) => consumed tag t.
// Numerics bit-identical to v4 (passed): same packing, same summation
// order, same RNG; only instruction order changed.

#define H     1024
#define NSTEP 8192
#define NWG   512
#define BLK   64
#define NROW  25   // 0-7 Wih1 (4 gates x 2 units), 8-15 Whh0, 16-23 Whh1, 24 W2

typedef _Float16 h2 __attribute__((ext_vector_type(2)));
typedef _Float16 h8 __attribute__((ext_vector_type(8)));

union U32H2 { uint32_t u; h2 v; };

__device__ __forceinline__ unsigned long long pack_vt(float v0, float v1, uint32_t tag){
  U32H2 p; p.v.x = (_Float16)v0; p.v.y = (_Float16)v1;
  return ((unsigned long long)tag << 32) | (unsigned long long)p.u;
}

// Exact JAX threefry2x32.
__device__ __forceinline__ uint2 tf2x32(uint32_t k0, uint32_t k1, uint32_t x0, uint32_t x1){
  uint32_t k2 = k0 ^ k1 ^ 0x1BD11BDAu;
  x0 += k0; x1 += k1;
#define TFR(r) { x0 += x1; x1 = (x1 << (r)) | (x1 >> (32 - (r))); x1 ^= x0; }
  TFR(13) TFR(15) TFR(26) TFR(6)
  x0 += k1; x1 += k2 + 1u;
  TFR(17) TFR(29) TFR(16) TFR(24)
  x0 += k2; x1 += k0 + 2u;
  TFR(13) TFR(15) TFR(26) TFR(6)
  x0 += k0; x1 += k1 + 3u;
  TFR(17) TFR(29) TFR(16) TFR(24)
  x0 += k1; x1 += k2 + 4u;
  TFR(13) TFR(15) TFR(26) TFR(6)
  x0 += k2; x1 += k0 + 5u;
#undef TFR
  uint2 r; r.x = x0; r.y = x1; return r;
}

// keys = threefry_split(key(42), 8192)
__device__ __forceinline__ uint32_t jax_word(uint32_t i){
  return (i < 8192u) ? tf2x32(0u, 42u, i, i + 8192u).x
                     : tf2x32(0u, 42u, i - 8192u, i).y;
}

__device__ __forceinline__ float wred64(float x){
  #pragma unroll
  for(int off = 32; off > 0; off >>= 1) x += __shfl_xor(x, off, 64);
  return x;
}

#if __has_builtin(__builtin_amdgcn_fdot2)
__device__ __forceinline__ float fdot2f(h2 a, h2 b, float c){ return __builtin_amdgcn_fdot2(a, b, c, false); }
#else
__device__ __forceinline__ float fdot2f(h2 a, h2 b, float c){
  return (float)a.x * (float)b.x + (float)a.y * (float)b.y + c;
}
#endif

__device__ __forceinline__ float sigm(float x){
  x = fminf(fmaxf(x, -30.f), 30.f);
  return 1.f / (1.f + __expf(-x));
}
__device__ __forceinline__ float tanh_f(float x){
  x = fminf(fmaxf(x, -15.f), 15.f);
  float e = __expf(2.f * x);
  return (e - 1.f) / (e + 1.f);
}

__device__ __forceinline__ unsigned long long ld_slot(const unsigned long long* p){
  return __hip_atomic_load((unsigned long long*)p, __ATOMIC_RELAXED, __HIP_MEMORY_SCOPE_AGENT);
}

// Batched initial issue of this lane's 8 slots.
__device__ __forceinline__ void issue8(unsigned long long* pv,
                                       const unsigned long long* p0,
                                       const unsigned long long* p1){
  #pragma unroll
  for(int k = 0; k < 4; k++){
    pv[k]     = ld_slot(p0 + k);
    pv[4 + k] = ld_slot(p1 + k);
  }
}

// v1's PROVEN lazy spin: per-slot sequential, reload ONLY the stale slot,
// s_sleep backoff. Cheap when initial loads are fresh (the design target).
__device__ __forceinline__ void spin8(unsigned long long* pv,
                                      const unsigned long long* p0,
                                      const unsigned long long* p1,
                                      uint32_t tag){
  #pragma unroll
  for(int k = 0; k < 8; k++){
    const unsigned long long* p = (k < 4) ? (p0 + k) : (p1 + (k - 4));
    while((uint32_t)(pv[k] >> 32) != tag){
      __builtin_amdgcn_s_sleep(1);
      pv[k] = ld_slot(p);
    }
  }
}

__device__ __forceinline__ void unpack8(const unsigned long long* pv, h2* hv){
  #pragma unroll
  for(int k = 0; k < 8; k++){
    U32H2 u; u.u = (uint32_t)pv[k];
    hv[k] = u.v;
  }
}

// Row dot partial: lane l covers h2 [4l,4l+4) and [256+4l,+4): two b128
// LDS reads, lane stride 16B -> conflict-free.
__device__ __forceinline__ float row_part(const h2* __restrict__ wrow, int lane, const h2* hv){
  h8 wl = *(const h8*)(wrow + (lane << 2));
  h8 wh = *(const h8*)(wrow + 256 + (lane << 2));
  float a0 = 0.f, a1 = 0.f;
  h2 w;
  w = __builtin_shufflevector(wl, wl, 0, 1); a0 = fdot2f(w, hv[0], a0);
  w = __builtin_shufflevector(wl, wl, 2, 3); a1 = fdot2f(w, hv[1], a1);
  w = __builtin_shufflevector(wl, wl, 4, 5); a0 = fdot2f(w, hv[2], a0);
  w = __builtin_shufflevector(wl, wl, 6, 7); a1 = fdot2f(w, hv[3], a1);
  w = __builtin_shufflevector(wh, wh, 0, 1); a0 = fdot2f(w, hv[4], a0);
  w = __builtin_shufflevector(wh, wh, 2, 3); a1 = fdot2f(w, hv[5], a1);
  w = __builtin_shufflevector(wh, wh, 4, 5); a0 = fdot2f(w, hv[6], a0);
  w = __builtin_shufflevector(wh, wh, 6, 7); a1 = fdot2f(w, hv[7], a1);
  return a0 + a1;
}

__global__ void __launch_bounds__(BLK)
lstm_persist(const float* __restrict__ ctx,  const float* __restrict__ W1p,  const float* __restrict__ b1p,
             const float* __restrict__ Wih0, const float* __restrict__ Whh0,
             const float* __restrict__ bih0, const float* __restrict__ bhh0,
             const float* __restrict__ Wih1, const float* __restrict__ Whh1,
             const float* __restrict__ bih1, const float* __restrict__ bhh1,
             const float* __restrict__ W2p,  const float* __restrict__ b2p,
             float* __restrict__ out,
             unsigned long long* __restrict__ h0boot,   // 512 (bootstrap only)
             unsigned long long* __restrict__ h1base,   // [2][512] parity
             unsigned long long* __restrict__ cbase)    // [2][2][512] parity x branch
{
  __shared__ h2 w[NROW][H/2];   // 51.2 KB

  const int lane = threadIdx.x;   // single wave per WG
  const int wg   = blockIdx.x;
  const int j0   = wg << 1;       // this wave's two h-units: j0, j0+1

  // ---- one-time: stage 25 rows as f16 (coalesced float4 reads)
  #pragma unroll 1
  for(int r = 0; r < NROW; r++){
    const float* rowp;
    if(r < 8)      { int g = r & 3,        j = j0 + (r >> 2);        rowp = Wih1 + (size_t)(g*H + j)*H; }
    else if(r < 16){ int rr = r - 8;  int g = rr & 3, j = j0 + (rr >> 2); rowp = Whh0 + (size_t)(g*H + j)*H; }
    else if(r < 24){ int rr = r - 16; int g = rr & 3, j = j0 + (rr >> 2); rowp = Whh1 + (size_t)(g*H + j)*H; }
    else           rowp = W2p;
    const float4* s4 = (const float4*)rowp;
    #pragma unroll
    for(int it = 0; it < 4; it++){
      float4 f = s4[lane + (it << 6)];
      h2 pa; pa.x = (_Float16)f.x; pa.y = (_Float16)f.y;
      h2 pb; pb.x = (_Float16)f.z; pb.y = (_Float16)f.w;
      const int ci = (lane + (it << 6)) << 1;
      w[r][ci] = pa; w[r][ci + 1] = pb;
    }
  }
  __syncthreads();

  // per-wave scalars for both units (uniform across lanes)
  float b0g[8], b1g[8], w0g[8];
  #pragma unroll
  for(int e = 0; e < 2; e++){
    const int j = j0 + e;
    #pragma unroll
    for(int g = 0; g < 4; g++){
      b0g[4*e + g] = bih0[g*H + j] + bhh0[g*H + j];
      b1g[4*e + g] = bih1[g*H + j] + bhh1[g*H + j];
      w0g[4*e + g] = Wih0[g*H + j];
    }
  }
  const float b2v = b2p[0];

  // x0 = W1 @ context + b1
  float xacc = 0.f;
  for(int c = lane; c < 512; c += 64) xacc += W1p[c] * ctx[c];
  const float x0 = wred64(xacc) + b1p[0];

  float c0[2], c1[2] = {0.f, 0.f}, logp = 0.f;
  float c0A[2], c0B[2];

  // h0(0) from x0; publish bootstrap (tag 1)
  {
    float h0v[2];
    #pragma unroll
    for(int e = 0; e < 2; e++){
      float gi = sigm (w0g[4*e+0]*x0 + b0g[4*e+0]);
      float gg = tanh_f(w0g[4*e+2]*x0 + b0g[4*e+2]);
      float go = sigm (w0g[4*e+3]*x0 + b0g[4*e+3]);
      c0[e] = gi * gg;
      h0v[e] = go * tanh_f(c0[e]);
    }
    if(lane == 0)
      __hip_atomic_store(&h0boot[wg], pack_vt(h0v[0], h0v[1], 1u),
                         __ATOMIC_RELAXED, __HIP_MEMORY_SCOPE_AGENT);
  }

  h2 hv0[8], hv1[8];
  unsigned long long pvH[8], pvA[8], pvB[8];

  // poll full h0(0) (v1 lazy poll on bootstrap buffer)
  {
    const unsigned long long* p0 = h0boot + (lane << 2);
    const unsigned long long* p1 = h0boot + 256 + (lane << 2);
    issue8(pvH, p0, p1);
    spin8(pvH, p0, p1, 1u);
    unpack8(pvH, hv0);
  }

  // ---- pre-loop: candidates h0(1)|s'=0,1 FIRST (tag 2 -> parity 0) ----
  {
    float a0v[8];
    #pragma unroll
    for(int r = 0; r < 8; r++) a0v[r] = row_part(&w[8 + r][0], lane, hv0);
    #pragma unroll
    for(int off = 32; off > 0; off >>= 1){
      #pragma unroll
      for(int r = 0; r < 8; r++) a0v[r] += __shfl_xor(a0v[r], off, 64);
    }
    float hA[2], hB[2];
    #pragma unroll
    for(int e = 0; e < 2; e++){
      float gi = sigm (a0v[4*e+0] + b0g[4*e+0]);
      float gf = sigm (a0v[4*e+1] + b0g[4*e+1]);
      float gg = tanh_f(a0v[4*e+2] + b0g[4*e+2]);
      float go = sigm (a0v[4*e+3] + b0g[4*e+3]);
      c0A[e] = gf*c0[e] + gi*gg; hA[e] = go * tanh_f(c0A[e]);
      float gi1 = sigm (a0v[4*e+0] + w0g[4*e+0] + b0g[4*e+0]);
      float gf1 = sigm (a0v[4*e+1] + w0g[4*e+1] + b0g[4*e+1]);
      float gg1 = tanh_f(a0v[4*e+2] + w0g[4*e+2] + b0g[4*e+2]);
      float go1 = sigm (a0v[4*e+3] + w0g[4*e+3] + b0g[4*e+3]);
      c0B[e] = gf1*c0[e] + gi1*gg1; hB[e] = go1 * tanh_f(c0B[e]);
    }
    if(lane == 0){
      __hip_atomic_store(cbase + wg,       pack_vt(hA[0], hA[1], 2u),
                         __ATOMIC_RELAXED, __HIP_MEMORY_SCOPE_AGENT);
      __hip_atomic_store(cbase + 512 + wg, pack_vt(hB[0], hB[1], 2u),
                         __ATOMIC_RELAXED, __HIP_MEMORY_SCOPE_AGENT);
    }
  }

  // ---- pre-loop: h1(0) LAST (tag 1 -> parity 1) ----
  {
    float s1[8];
    #pragma unroll
    for(int r = 0; r < 8; r++) s1[r] = row_part(&w[r][0], lane, hv0);
    #pragma unroll
    for(int off = 32; off > 0; off >>= 1){
      #pragma unroll
      for(int r = 0; r < 8; r++) s1[r] += __shfl_xor(s1[r], off, 64);
    }
    float h1v[2];
    #pragma unroll
    for(int e = 0; e < 2; e++){
      float gi = sigm (s1[4*e+0] + b1g[4*e+0]);   // a1(-1)=0
      float gf = sigm (s1[4*e+1] + b1g[4*e+1]);
      float gg = tanh_f(s1[4*e+2] + b1g[4*e+2]);
      float go = sigm (s1[4*e+3] + b1g[4*e+3]);
      c1[e] = gf*c1[e] + gi*gg;
      h1v[e] = go * tanh_f(c1[e]);
    }
    if(lane == 0)
      __hip_atomic_store(h1base + 512 + wg, pack_vt(h1v[0], h1v[1], 1u),
                         __ATOMIC_RELAXED, __HIP_MEMORY_SCOPE_AGENT);
  }

  // u(0)
  float u;
  {
    const uint32_t kk0 = jax_word(0u), kk1 = jax_word(1u);
    const uint32_t bits = tf2x32(kk0, kk1, 0u, 0u).x;
    u = __uint_as_float((bits >> 9) | 0x3f800000u) - 1.0f;
  }

  #pragma unroll 1
  for(int t = 0; t < NSTEP; t++){
    const uint32_t tagH = (uint32_t)t + 1u;   // h1(t)
    const uint32_t tagC = (uint32_t)t + 2u;   // candidates of h0(t+1)

    const unsigned long long* h1b = h1base + ((size_t)(tagH & 1u) << 9);
    const unsigned long long* cAb = cbase  + ((size_t)(tagC & 1u) << 10);
    const unsigned long long* cBb = cAb + 512;

    const unsigned long long* hp0 = h1b + (lane << 2);
    const unsigned long long* hp1 = h1b + 256 + (lane << 2);
    const unsigned long long* ap0 = cAb + (lane << 2);
    const unsigned long long* ap1 = cAb + 256 + (lane << 2);
    const unsigned long long* bp0 = cBb + (lane << 2);
    const unsigned long long* bp1 = cBb + 256 + (lane << 2);

    // ---- A: poll h1(t) (v1 lazy poll) ----
    issue8(pvH, hp0, hp1);
    spin8(pvH, hp0, hp1, tagH);
    unpack8(pvH, hv1);

    // cands were stored BEFORE h1 by producers: visible now. Issue loads;
    // RT hides under B.
    issue8(pvA, ap0, ap1);
    issue8(pvB, bp0, bp1);

    // ---- B: resolve z -> p -> s(t) ----
    float z = row_part(&w[24][0], lane, hv1);
    z = wred64(z) + b2v;
    const float p = sigm(z);
    const float sv = (u < p) ? 1.f : 0.f;
    logp += sv * __logf(p) + (1.f - sv) * __logf(1.f - p);
    if(wg == 0 && lane == 0) out[t] = sv;

    // ---- C: select candidate h0(t+1) (fresh; typically zero respins) ----
    const bool sb = (sv != 0.f);
    {
      const unsigned long long* sp0 = sb ? bp0 : ap0;
      const unsigned long long* sp1 = sb ? bp1 : ap1;
      unsigned long long ps[8];
      #pragma unroll
      for(int k = 0; k < 8; k++) ps[k] = sb ? pvB[k] : pvA[k];
      spin8(ps, sp0, sp1, tagC);
      unpack8(ps, hv0);
    }
    #pragma unroll
    for(int e = 0; e < 2; e++) c0[e] = sb ? c0B[e] : c0A[e];

    // ---- E (FIRST publish): Whh0 rows -> candidates h0(t+2) (tag t+3) ----
    {
      float a0v[8];
      #pragma unroll
      for(int r = 0; r < 8; r++) a0v[r] = row_part(&w[8 + r][0], lane, hv0);
      #pragma unroll
      for(int off = 32; off > 0; off >>= 1){
        #pragma unroll
        for(int r = 0; r < 8; r++) a0v[r] += __shfl_xor(a0v[r], off, 64);
      }
      float hA[2], hB[2];
      #pragma unroll
      for(int e = 0; e < 2; e++){
        float gi = sigm (a0v[4*e+0] + b0g[4*e+0]);
        float gf = sigm (a0v[4*e+1] + b0g[4*e+1]);
        float gg = tanh_f(a0v[4*e+2] + b0g[4*e+2]);
        float go = sigm (a0v[4*e+3] + b0g[4*e+3]);
        c0A[e] = gf*c0[e] + gi*gg; hA[e] = go * tanh_f(c0A[e]);
        float gi1 = sigm (a0v[4*e+0] + w0g[4*e+0] + b0g[4*e+0]);
        float gf1 = sigm (a0v[4*e+1] + w0g[4*e+1] + b0g[4*e+1]);
        float gg1 = tanh_f(a0v[4*e+2] + w0g[4*e+2] + b0g[4*e+2]);
        float go1 = sigm (a0v[4*e+3] + w0g[4*e+3] + b0g[4*e+3]);
        c0B[e] = gf1*c0[e] + gi1*gg1; hB[e] = go1 * tanh_f(c0B[e]);
      }
      if(lane == 0){
        unsigned long long* cp = cbase + ((size_t)(tagH & 1u) << 10);  // parity (t+3)&1
        __hip_atomic_store(cp + wg,       pack_vt(hA[0], hA[1], tagC + 1u),
                           __ATOMIC_RELAXED, __HIP_MEMORY_SCOPE_AGENT);
        __hip_atomic_store(cp + 512 + wg, pack_vt(hB[0], hB[1], tagC + 1u),
                           __ATOMIC_RELAXED, __HIP_MEMORY_SCOPE_AGENT);
      }
    }

    // ---- D (LAST publish): 16 rows -> h1(t+1) (tag t+2) ----
    {
      float rr[16];
      #pragma unroll
      for(int r = 0; r < 8; r++) rr[r]     = row_part(&w[r][0],      lane, hv0);  // Wih1 @ h0(t+1)
      #pragma unroll
      for(int r = 0; r < 8; r++) rr[8 + r] = row_part(&w[16 + r][0], lane, hv1);  // Whh1 @ h1(t)
      #pragma unroll
      for(int off = 32; off > 0; off >>= 1){
        #pragma unroll
        for(int r = 0; r < 16; r++) rr[r] += __shfl_xor(rr[r], off, 64);
      }
      float h1v[2];
      #pragma unroll
      for(int e = 0; e < 2; e++){
        float gi = sigm (rr[4*e+0] + rr[8+4*e+0] + b1g[4*e+0]);
        float gf = sigm (rr[4*e+1] + rr[8+4*e+1] + b1g[4*e+1]);
        float gg = tanh_f(rr[4*e+2] + rr[8+4*e+2] + b1g[4*e+2]);
        float go = sigm (rr[4*e+3] + rr[8+4*e+3] + b1g[4*e+3]);
        c1[e] = gf*c1[e] + gi*gg;
        h1v[e] = go * tanh_f(c1[e]);
      }
      if(lane == 0)
        __hip_atomic_store(h1base + ((size_t)(tagC & 1u) << 9) + wg,
                           pack_vt(h1v[0], h1v[1], tagC),
                           __ATOMIC_RELAXED, __HIP_MEMORY_SCOPE_AGENT);
    }

    // ---- F: shadow: RNG u(t+1) ----
    {
      const uint32_t tn = (uint32_t)t + 1u;
      const uint32_t kk0 = jax_word(2u*tn), kk1 = jax_word(2u*tn + 1u);
      const uint32_t bits = tf2x32(kk0, kk1, 0u, 0u).x;
      u = __uint_as_float((bits >> 9) | 0x3f800000u) - 1.0f;
    }
  }

  if(wg == 0 && lane == 0) out[NSTEP] = logp;
}

extern "C" void kernel_launch(void* const* d_in, const int* in_sizes, int n_in,
                              void* d_out, int out_size, void* d_ws, size_t ws_size,
                              hipStream_t stream){
  unsigned long long* ws = (unsigned long long*)d_ws;
  unsigned long long* h0boot = ws;            // 512
  unsigned long long* h1base = ws + 512;      // 2 x 512
  unsigned long long* cbase  = ws + 1536;     // 2 x 2 x 512
  hipLaunchKernelGGL(lstm_persist, dim3(NWG), dim3(BLK), 0, stream,
    (const float*)d_in[0],  (const float*)d_in[1],  (const float*)d_in[2],
    (const float*)d_in[3],  (const float*)d_in[4],  (const float*)d_in[5],  (const float*)d_in[6],
    (const float*)d_in[7],  (const float*)d_in[8],  (const float*)d_in[9],  (const float*)d_in[10],
    (const float*)d_in[11], (const float*)d_in[12],
    (float*)d_out, h0boot, h1base, cbase);
}

// Round 5
// 32888.184 us; speedup vs baseline: 1.9634x; 1.9634x over previous
//
#include <hip/hip_runtime.h>
#include <stdint.h>
#include <math.h>

// Persistent barrier-free 2-layer LSTM rollout, MI355X (gfx950).
// v6 = EXACT v1 structure (verified 33.3ms; the only scheme this fabric
// tolerates — v2-v5 showed any extra polled array or eager reload causes
// coherent-read storms) + ONE poll micro-fix:
//   v1's spin walked slots 0..7 sequentially; each stale slot cost a
//   DEPENDENT LLC round-trip (~0.25us). New poll:
//     phase 1: lazy sentinel spin on slot 0 (v1's exact waiting-traffic)
//     phase 2: ONE batched concurrent reload of the stale remainder (~1 RT)
//     phase 3: v1 lazy walk for rare stragglers
//   Worst case = v1 + 1 RT; typical removes the serialized tail.
// Plus: logp/out moved after the h0 publish (trims ~40cy off critical).
// Numerics bit-identical to v1.
//
// 512 WGs x 64 thr (1 wave); wave w owns h-units {2w, 2w+1} of both layers.
// Critical chain/step: poll h0 -> 8 gate rows -> publish h1 ->
//                      poll h1 -> W2 row -> cell0 -> publish h0.
// Whh0/Whh1 rows + threefry RNG run post-publish (shadow time).

#define H     1024
#define NSTEP 8192
#define NWG   512
#define BLK   64
#define NROW  25   // 0-7 Wih1 (4 gates x 2 units), 8-15 Whh0, 16-23 Whh1, 24 W2

typedef _Float16 h2 __attribute__((ext_vector_type(2)));
typedef _Float16 h8 __attribute__((ext_vector_type(8)));

union U32H2 { uint32_t u; h2 v; };

__device__ __forceinline__ unsigned long long pack_vt(float v0, float v1, uint32_t tag){
  U32H2 p; p.v.x = (_Float16)v0; p.v.y = (_Float16)v1;
  return ((unsigned long long)tag << 32) | (unsigned long long)p.u;
}

// Exact JAX threefry2x32.
__device__ __forceinline__ uint2 tf2x32(uint32_t k0, uint32_t k1, uint32_t x0, uint32_t x1){
  uint32_t k2 = k0 ^ k1 ^ 0x1BD11BDAu;
  x0 += k0; x1 += k1;
#define TFR(r) { x0 += x1; x1 = (x1 << (r)) | (x1 >> (32 - (r))); x1 ^= x0; }
  TFR(13) TFR(15) TFR(26) TFR(6)
  x0 += k1; x1 += k2 + 1u;
  TFR(17) TFR(29) TFR(16) TFR(24)
  x0 += k2; x1 += k0 + 2u;
  TFR(13) TFR(15) TFR(26) TFR(6)
  x0 += k0; x1 += k1 + 3u;
  TFR(17) TFR(29) TFR(16) TFR(24)
  x0 += k1; x1 += k2 + 4u;
  TFR(13) TFR(15) TFR(26) TFR(6)
  x0 += k2; x1 += k0 + 5u;
#undef TFR
  uint2 r; r.x = x0; r.y = x1; return r;
}

// keys = threefry_split(key(42), 8192)
__device__ __forceinline__ uint32_t jax_word(uint32_t i){
  return (i < 8192u) ? tf2x32(0u, 42u, i, i + 8192u).x
                     : tf2x32(0u, 42u, i - 8192u, i).y;
}

__device__ __forceinline__ float wred64(float x){
  #pragma unroll
  for(int off = 32; off > 0; off >>= 1) x += __shfl_xor(x, off, 64);
  return x;
}

#if __has_builtin(__builtin_amdgcn_fdot2)
__device__ __forceinline__ float fdot2f(h2 a, h2 b, float c){ return __builtin_amdgcn_fdot2(a, b, c, false); }
#else
__device__ __forceinline__ float fdot2f(h2 a, h2 b, float c){
  return (float)a.x * (float)b.x + (float)a.y * (float)b.y + c;
}
#endif

__device__ __forceinline__ float sigm(float x){
  x = fminf(fmaxf(x, -30.f), 30.f);
  return 1.f / (1.f + __expf(-x));
}
__device__ __forceinline__ float tanh_f(float x){
  x = fminf(fmaxf(x, -15.f), 15.f);
  float e = __expf(2.f * x);
  return (e - 1.f) / (e + 1.f);
}

__device__ __forceinline__ unsigned long long ld_slot(const unsigned long long* p){
  return __hip_atomic_load((unsigned long long*)p, __ATOMIC_RELAXED, __HIP_MEMORY_SCOPE_AGENT);
}

// Poll this lane's 8 slots (fragment pairs [4l,4l+4) and [256+4l,+4)).
// phase 1: lazy sentinel spin (slot 0) — v1's exact waiting-traffic profile
// phase 2: one batched concurrent reload of stale remainder (~1 LLC RT)
// phase 3: v1 lazy walk for rare stragglers
__device__ __forceinline__ void poll_h(const unsigned long long* __restrict__ buf,
                                       uint32_t tag, int lane, h2* hv){
  const unsigned long long* p0 = buf + (lane << 2);
  const unsigned long long* p1 = buf + 256 + (lane << 2);
  unsigned long long pv[8];
  #pragma unroll
  for(int k = 0; k < 4; k++) pv[k]     = ld_slot(p0 + k);
  #pragma unroll
  for(int k = 0; k < 4; k++) pv[4 + k] = ld_slot(p1 + k);

  // phase 1: sentinel
  while((uint32_t)(pv[0] >> 32) != tag){
    __builtin_amdgcn_s_sleep(1);
    pv[0] = ld_slot(p0);
  }

  // phase 2: batched refresh of whatever is still stale (single issue burst)
  bool any = false;
  #pragma unroll
  for(int k = 1; k < 8; k++) any |= ((uint32_t)(pv[k] >> 32) != tag);
  if(any){
    #pragma unroll
    for(int k = 1; k < 8; k++){
      if((uint32_t)(pv[k] >> 32) != tag){
        const unsigned long long* p = (k < 4) ? (p0 + k) : (p1 + (k - 4));
        pv[k] = ld_slot(p);
      }
    }
    // phase 3: stragglers (rare) — v1 lazy walk
    #pragma unroll
    for(int k = 1; k < 8; k++){
      const unsigned long long* p = (k < 4) ? (p0 + k) : (p1 + (k - 4));
      while((uint32_t)(pv[k] >> 32) != tag){
        __builtin_amdgcn_s_sleep(1);
        pv[k] = ld_slot(p);
      }
    }
  }

  #pragma unroll
  for(int k = 0; k < 8; k++){
    U32H2 u; u.u = (uint32_t)pv[k];
    hv[k] = u.v;
  }
}

// Row dot partial: lane l covers h2 [4l,4l+4) and [256+4l,+4): two b128
// LDS reads, lane stride 16B -> conflict-free.
__device__ __forceinline__ float row_part(const h2* __restrict__ wrow, int lane, const h2* hv){
  h8 wl = *(const h8*)(wrow + (lane << 2));
  h8 wh = *(const h8*)(wrow + 256 + (lane << 2));
  float a0 = 0.f, a1 = 0.f;
  h2 w;
  w = __builtin_shufflevector(wl, wl, 0, 1); a0 = fdot2f(w, hv[0], a0);
  w = __builtin_shufflevector(wl, wl, 2, 3); a1 = fdot2f(w, hv[1], a1);
  w = __builtin_shufflevector(wl, wl, 4, 5); a0 = fdot2f(w, hv[2], a0);
  w = __builtin_shufflevector(wl, wl, 6, 7); a1 = fdot2f(w, hv[3], a1);
  w = __builtin_shufflevector(wh, wh, 0, 1); a0 = fdot2f(w, hv[4], a0);
  w = __builtin_shufflevector(wh, wh, 2, 3); a1 = fdot2f(w, hv[5], a1);
  w = __builtin_shufflevector(wh, wh, 4, 5); a0 = fdot2f(w, hv[6], a0);
  w = __builtin_shufflevector(wh, wh, 6, 7); a1 = fdot2f(w, hv[7], a1);
  return a0 + a1;
}

__global__ void __launch_bounds__(BLK)
lstm_persist(const float* __restrict__ ctx,  const float* __restrict__ W1p,  const float* __restrict__ b1p,
             const float* __restrict__ Wih0, const float* __restrict__ Whh0,
             const float* __restrict__ bih0, const float* __restrict__ bhh0,
             const float* __restrict__ Wih1, const float* __restrict__ Whh1,
             const float* __restrict__ bih1, const float* __restrict__ bhh1,
             const float* __restrict__ W2p,  const float* __restrict__ b2p,
             float* __restrict__ out,
             unsigned long long* __restrict__ h0buf,
             unsigned long long* __restrict__ h1buf)
{
  __shared__ h2 w[NROW][H/2];   // 51.2 KB (<64KB/block cap); 2 WGs/CU

  const int lane = threadIdx.x;   // single wave per WG
  const int wg   = blockIdx.x;
  const int j0   = wg << 1;       // this wave's two h-units: j0, j0+1

  // ---- one-time: stage 25 rows as f16 (coalesced float4 reads)
  #pragma unroll 1
  for(int r = 0; r < NROW; r++){
    const float* rowp;
    if(r < 8)      { int g = r & 3,        j = j0 + (r >> 2);        rowp = Wih1 + (size_t)(g*H + j)*H; }
    else if(r < 16){ int rr = r - 8;  int g = rr & 3, j = j0 + (rr >> 2); rowp = Whh0 + (size_t)(g*H + j)*H; }
    else if(r < 24){ int rr = r - 16; int g = rr & 3, j = j0 + (rr >> 2); rowp = Whh1 + (size_t)(g*H + j)*H; }
    else           rowp = W2p;
    const float4* s4 = (const float4*)rowp;
    #pragma unroll
    for(int it = 0; it < 4; it++){
      float4 f = s4[lane + (it << 6)];
      h2 pa; pa.x = (_Float16)f.x; pa.y = (_Float16)f.y;
      h2 pb; pb.x = (_Float16)f.z; pb.y = (_Float16)f.w;
      const int ci = (lane + (it << 6)) << 1;
      w[r][ci] = pa; w[r][ci + 1] = pb;
    }
  }
  __syncthreads();

  // per-wave scalars for both units (uniform across lanes)
  float b0g[8], b1g[8], w0g[8];
  #pragma unroll
  for(int e = 0; e < 2; e++){
    const int j = j0 + e;
    #pragma unroll
    for(int g = 0; g < 4; g++){
      b0g[4*e + g] = bih0[g*H + j] + bhh0[g*H + j];
      b1g[4*e + g] = bih1[g*H + j] + bhh1[g*H + j];
      w0g[4*e + g] = Wih0[g*H + j];
    }
  }
  const float b2v = b2p[0];

  // x0 = W1 @ context + b1
  float xacc = 0.f;
  for(int c = lane; c < 512; c += 64) xacc += W1p[c] * ctx[c];
  const float x0 = wred64(xacc) + b1p[0];

  float c0[2], c1[2] = {0.f, 0.f}, logp = 0.f;
  float a0[8];
  float a1[8] = {0.f,0.f,0.f,0.f,0.f,0.f,0.f,0.f};

  // h0(0) from x0 for both units
  {
    float h0v[2];
    #pragma unroll
    for(int e = 0; e < 2; e++){
      float gi = sigm (w0g[4*e+0]*x0 + b0g[4*e+0]);
      float gg = tanh_f(w0g[4*e+2]*x0 + b0g[4*e+2]);
      float go = sigm (w0g[4*e+3]*x0 + b0g[4*e+3]);
      c0[e] = gi * gg;
      h0v[e] = go * tanh_f(c0[e]);
    }
    if(lane == 0)
      __hip_atomic_store(&h0buf[wg], pack_vt(h0v[0], h0v[1], 1u),
                         __ATOMIC_RELAXED, __HIP_MEMORY_SCOPE_AGENT);
  }

  h2 hv[8];
  float u = 0.f;

  #pragma unroll 1
  for(int t = 0; t < NSTEP; t++){
    const uint32_t tt = (uint32_t)t;

    // ================= P1: consume h0(t) =================
    poll_h(h0buf, tt + 1u, lane, hv);

    // critical: 8 layer-1 gate rows (Wih1, both units)
    float s1[8];
    #pragma unroll
    for(int r = 0; r < 8; r++) s1[r] = row_part(&w[r][0], lane, hv);
    #pragma unroll
    for(int off = 32; off > 0; off >>= 1){
      #pragma unroll
      for(int r = 0; r < 8; r++) s1[r] += __shfl_xor(s1[r], off, 64);
    }
    {
      float h1v[2];
      #pragma unroll
      for(int e = 0; e < 2; e++){
        float gi = sigm (s1[4*e+0] + a1[4*e+0] + b1g[4*e+0]);
        float gf = sigm (s1[4*e+1] + a1[4*e+1] + b1g[4*e+1]);
        float gg = tanh_f(s1[4*e+2] + a1[4*e+2] + b1g[4*e+2]);
        float go = sigm (s1[4*e+3] + a1[4*e+3] + b1g[4*e+3]);
        c1[e] = gf*c1[e] + gi*gg;
        h1v[e] = go * tanh_f(c1[e]);
      }
      if(lane == 0)
        __hip_atomic_store(&h1buf[wg], pack_vt(h1v[0], h1v[1], tt + 1u),
                           __ATOMIC_RELAXED, __HIP_MEMORY_SCOPE_AGENT);
    }

    // shadow: RNG + 8 Whh0 rows (a0 for P2's cell0)
    {
      const uint32_t kk0 = jax_word(2u*tt), kk1 = jax_word(2u*tt + 1u);
      const uint32_t bits = tf2x32(kk0, kk1, 0u, 0u).x;
      u = __uint_as_float((bits >> 9) | 0x3f800000u) - 1.0f;
    }
    float sa[8];
    #pragma unroll
    for(int r = 0; r < 8; r++) sa[r] = row_part(&w[8 + r][0], lane, hv);
    #pragma unroll
    for(int off = 32; off > 0; off >>= 1){
      #pragma unroll
      for(int r = 0; r < 8; r++) sa[r] += __shfl_xor(sa[r], off, 64);
    }
    #pragma unroll
    for(int r = 0; r < 8; r++) a0[r] = sa[r];

    // ================= P2: consume h1(t) =================
    poll_h(h1buf, tt + 1u, lane, hv);

    // critical: W2 row -> p,s -> cell0 -> publish h0(t+1)
    float z = row_part(&w[24][0], lane, hv);
    z = wred64(z) + b2v;
    const float p = sigm(z);
    const float s = (u < p) ? 1.f : 0.f;
    {
      float h0v[2];
      #pragma unroll
      for(int e = 0; e < 2; e++){
        float gi = sigm (a0[4*e+0] + w0g[4*e+0]*s + b0g[4*e+0]);
        float gf = sigm (a0[4*e+1] + w0g[4*e+1]*s + b0g[4*e+1]);
        float gg = tanh_f(a0[4*e+2] + w0g[4*e+2]*s + b0g[4*e+2]);
        float go = sigm (a0[4*e+3] + w0g[4*e+3]*s + b0g[4*e+3]);
        c0[e] = gf*c0[e] + gi*gg;
        h0v[e] = go * tanh_f(c0[e]);
      }
      if(lane == 0)
        __hip_atomic_store(&h0buf[wg], pack_vt(h0v[0], h0v[1], tt + 2u),
                           __ATOMIC_RELAXED, __HIP_MEMORY_SCOPE_AGENT);
    }

    // moved off critical path: logp/out after the publish
    logp += s * __logf(p) + (1.f - s) * __logf(1.f - p);
    if(wg == 0 && lane == 0) out[t] = s;

    // shadow: 8 Whh1 rows (a1 for next step's P1)
    float sb[8];
    #pragma unroll
    for(int r = 0; r < 8; r++) sb[r] = row_part(&w[16 + r][0], lane, hv);
    #pragma unroll
    for(int off = 32; off > 0; off >>= 1){
      #pragma unroll
      for(int r = 0; r < 8; r++) sb[r] += __shfl_xor(sb[r], off, 64);
    }
    #pragma unroll
    for(int r = 0; r < 8; r++) a1[r] = sb[r];
  }

  if(wg == 0 && lane == 0) out[NSTEP] = logp;
}

extern "C" void kernel_launch(void* const* d_in, const int* in_sizes, int n_in,
                              void* d_out, int out_size, void* d_ws, size_t ws_size,
                              hipStream_t stream){
  unsigned long long* h0buf = (unsigned long long*)d_ws;   // 512 slots
  unsigned long long* h1buf = h0buf + 512;                 // 512 slots
  hipLaunchKernelGGL(lstm_persist, dim3(NWG), dim3(BLK), 0, stream,
    (const float*)d_in[0],  (const float*)d_in[1],  (const float*)d_in[2],
    (const float*)d_in[3],  (const float*)d_in[4],  (const float*)d_in[5],  (const float*)d_in[6],
    (const float*)d_in[7],  (const float*)d_in[8],  (const float*)d_in[9],  (const float*)d_in[10],
    (const float*)d_in[11], (const float*)d_in[12],
    (float*)d_out, h0buf, h1buf);
}